// Round 19
// baseline (10404.483 us; speedup 1.0000x reference)
//
#include <hip/hip_runtime.h>
#include <math.h>

// ---------------------------------------------------------------------------
// AE_control: B=1024, T=512, D=64, K=9, NUM_M=64, NUM_N=32, SCALE=1
// Encoder + argmin in f64 (np reference is f64). Per-chain accumulation:
// bias + cin-ascending, k-ascending (proven). f64 MFMA abandoned (3 fails).
// R19: R17 base + conv cin-loop unroll 2 (compiler pipelining window) +
// code_assign means transposed [m][c] in LDS (double2 broadcast reads).
// Decoder merged (R15), FC split-K. BC=256.
// ---------------------------------------------------------------------------

#define TB 512
#define BATCH 1024

// (nmat, C, C, 9) f32 -> (nmat, C, 9, C) f64: wT2[cin][k][cout]
__global__ __launch_bounds__(256) void transpose_w2_f64_kernel(
    const float* __restrict__ w, double* __restrict__ wT, int C, int nmat) {
  int total = nmat * C * C * 9;
  for (int i = blockIdx.x * blockDim.x + threadIdx.x; i < total;
       i += gridDim.x * blockDim.x) {
    int mat = i / (C * C * 9);
    int r = i % (C * C * 9);
    int cout = r / (C * 9);
    int rem = r % (C * 9);
    int cin = rem / 9;
    int k = rem % 9;
    wT[((mat * C + cin) * 9 + k) * C + cout] = (double)w[i];
  }
}

// (nmat, C, C, 9) f32 -> (nmat, 9, C, C) f32  [k][cin][cout]
__global__ __launch_bounds__(256) void transpose_w_f32_kernel(
    const float* __restrict__ w, float* __restrict__ wT, int C, int nmat) {
  int total = nmat * C * C * 9;
  for (int i = blockIdx.x * blockDim.x + threadIdx.x; i < total;
       i += gridDim.x * blockDim.x) {
    int mat = i / (C * C * 9);
    int r = i % (C * C * 9);
    int cout = r / (C * 9);
    int rem = r % (C * 9);
    int cin = rem / 9;
    int k = rem % 9;
    wT[mat * C * C * 9 + (k * C + cin) * C + cout] = w[i];
  }
}

// Streaming FMA over a 24-double window feeding 16 chains:
// acc[j-k] += w[k]*x[j], j ascending => per-chain k ascending.
template <typename F>
__device__ __forceinline__ void conv64_fma_stream(const double* __restrict__ xr,
                                                  const double (&w)[9],
                                                  F&& upd) {
#pragma unroll
  for (int j2 = 0; j2 < 24; j2 += 2) {
    double2 v = *(const double2*)&xr[j2];
#pragma unroll
    for (int k = 0; k < 9; ++k) {
      int ta = j2 - k;
      if (ta >= 0 && ta < 16) upd(ta, w[k], v.x);
    }
#pragma unroll
    for (int k = 0; k < 9; ++k) {
      int tb = j2 + 1 - k;
      if (tb >= 0 && tb < 16) upd(tb, w[k], v.y);
    }
  }
}

__device__ __forceinline__ void load9(const double* __restrict__ p,
                                      double (&w)[9]) {
#pragma unroll
  for (int k = 0; k < 9; ++k) w[k] = p[k * 64];
}

// 32-cin range of the conv body: lane = cout, wslab = 16-t slab.
// xs: LDS [64][72]. wT2: global [cin][9][64]. 2-buffer weight prefetch.
// unroll 2 -> 4-cin scheduler window for cross-iteration pipelining.
__device__ __forceinline__ void conv64_body_range(
    const double* __restrict__ xs, const double* __restrict__ wT2,
    double acc[16], int lane, int wslab, int cin0) {
  const double* wp0 = wT2 + lane;
  const double* xb = xs + wslab * 16;
  double wA[9], wB[9];
  load9(wp0 + cin0 * 576, wA);
  auto upd = [&](int t, double w, double x) { acc[t] = fma(w, x, acc[t]); };
#pragma unroll 2
  for (int cin = cin0; cin < cin0 + 32; cin += 2) {
    load9(wp0 + (cin + 1) * 576, wB);
    conv64_fma_stream(xb + cin * 72, wA, upd);
    if (cin + 2 < cin0 + 32) load9(wp0 + (cin + 2) * 576, wA);
    conv64_fma_stream(xb + (cin + 1) * 72, wB, upd);
  }
}

// enc0 fused block (f64): x f32 (BC,512) -> out f64 (BC,64,512). 256 thr.
__global__ __launch_bounds__(256, 1) void enc0_f64_kernel(
    const float* __restrict__ x, const float* __restrict__ w1,
    const float* __restrict__ b1, const double* __restrict__ w2T,
    const float* __restrict__ b2, const float* __restrict__ wsc,
    const float* __restrict__ bsc, double* __restrict__ out) {
  __shared__ double xs0[80];
  __shared__ double w1s[576];
  __shared__ double b1s[64];
  __shared__ double mid[64 * 72];
  int b = blockIdx.y;
  int t0 = blockIdx.x * 64;
  int tid = threadIdx.x;
  if (tid < 80) {
    int t = t0 - 8 + tid;
    xs0[tid] = (t >= 0 && t < TB) ? (double)x[b * TB + t] : 0.0;
  }
  for (int i = tid; i < 576; i += 256) w1s[i] = (double)w1[i];
  if (tid < 64) b1s[tid] = (double)b1[tid];
  __syncthreads();
  for (int e = tid; e < 64 * 72; e += 256) {
    int cout = e / 72, tt = e % 72;
    int t = t0 - 4 + tt;
    double acc = b1s[cout];
#pragma unroll
    for (int k = 0; k < 9; ++k) acc = fma(w1s[cout * 9 + k], xs0[tt + k], acc);
    mid[e] = (t >= 0 && t < TB) ? fmax(acc, 0.0) : 0.0;
  }
  __syncthreads();
  int wave = tid >> 6;
  int lane = tid & 63;
  double acc[16];
  double bz = (double)b2[lane];
#pragma unroll
  for (int t = 0; t < 16; ++t) acc[t] = bz;
  conv64_body_range(mid, w2T, acc, lane, wave, 0);
  conv64_body_range(mid, w2T, acc, lane, wave, 32);
  __syncthreads();  // mid reads done; reuse as transpose buffer [64][65]
  double* T = mid;
#pragma unroll
  for (int t = 0; t < 16; ++t) T[lane * 65 + wave * 16 + t] = acc[t];
  __syncthreads();
  for (int i = tid; i < 4096; i += 256) {
    int cout = i >> 6, tt = i & 63;
    double v = T[cout * 65 + tt] +
               fma((double)wsc[cout], xs0[8 + tt], (double)bsc[cout]);
    out[(b * 64 + cout) * TB + t0 + tt] = fmax(v, 0.0);
  }
}

// f64 conv 64->64, K=9, SAME. 256 thr, 4 waves x 16-t slabs.
template <bool SKIP>
__global__ __launch_bounds__(256, 1) void conv64_f64_kernel(
    const double* __restrict__ in, const double* __restrict__ wT2,
    const float* __restrict__ bias, const double* __restrict__ skip,
    double* __restrict__ out) {
  __shared__ double xs[64 * 72];
  int b = blockIdx.y;
  int t0 = blockIdx.x * 64;
  int tid = threadIdx.x;
  for (int i = tid; i < 64 * 72; i += 256) {
    int cin = i / 72, tt = i % 72;
    int t = t0 - 4 + tt;
    xs[i] = (t >= 0 && t < TB) ? in[(b * 64 + cin) * TB + t] : 0.0;
  }
  __syncthreads();
  int wave = tid >> 6;
  int lane = tid & 63;
  double acc[16];
  double bz = (double)bias[lane];
#pragma unroll
  for (int t = 0; t < 16; ++t) acc[t] = bz;
  conv64_body_range(xs, wT2, acc, lane, wave, 0);
  conv64_body_range(xs, wT2, acc, lane, wave, 32);
  __syncthreads();  // xs reads done; reuse as transpose buffer [64][65]
  double* T = xs;
#pragma unroll
  for (int t = 0; t < 16; ++t) T[lane * 65 + wave * 16 + t] = acc[t];
  __syncthreads();
  for (int i = tid; i < 4096; i += 256) {
    int cout = i >> 6, tt = i & 63;
    double v = T[cout * 65 + tt];
    if constexpr (SKIP) v += skip[(b * 64 + cout) * TB + t0 + tt];
    out[(b * 64 + cout) * TB + t0 + tt] = fmax(v, 0.0);
  }
}

// f32 conv 32->32 (decoder), K=9, SAME; blockIdx.z selects stream s/n.
template <bool SKIP>
__global__ __launch_bounds__(256) void conv32z_kernel(
    const float* __restrict__ in0, const float* __restrict__ in1,
    const float* __restrict__ wT, const float* __restrict__ bias,
    const float* __restrict__ sk0, const float* __restrict__ sk1,
    float* __restrict__ o0, float* __restrict__ o1) {
  constexpr int XW = 136;
  __shared__ float xs[32 * XW];
  const float* in = blockIdx.z ? in1 : in0;
  const float* skip = blockIdx.z ? sk1 : sk0;
  float* out = blockIdx.z ? o1 : o0;
  int b = blockIdx.y;
  int t0 = blockIdx.x * 128;
  int tid = threadIdx.x;
  for (int i = tid; i < 32 * XW; i += 256) {
    int cin = i / XW, tt = i % XW;
    int t = t0 - 4 + tt;
    xs[i] = (t >= 0 && t < TB) ? in[(b * 32 + cin) * TB + t] : 0.f;
  }
  __syncthreads();
  int wave = __builtin_amdgcn_readfirstlane(tid >> 6);
  int lane = tid & 63;
  int cbase = (wave & 1) * 16;
  int ttl = (wave >> 1) * 64 + lane;
  float acc[16];
#pragma unroll
  for (int j = 0; j < 16; ++j) acc[j] = bias[cbase + j];
  for (int cin = 0; cin < 32; ++cin) {
#pragma unroll
    for (int k = 0; k < 9; ++k) {
      float xv = xs[cin * XW + ttl + k];
      const float* wp = wT + (k * 32 + cin) * 32 + cbase;
#pragma unroll
      for (int j = 0; j < 16; ++j) acc[j] = fmaf(xv, wp[j], acc[j]);
    }
  }
  int t = t0 + ttl;
#pragma unroll
  for (int j = 0; j < 16; ++j) {
    float v = acc[j];
    if constexpr (SKIP) v += skip[(b * 32 + cbase + j) * TB + t];
    out[(b * 32 + cbase + j) * TB + t] = fmaxf(v, 0.f);
  }
}

// code_assign (f64 distances/argmin, f32 q). Means transposed to [m][c] in
// LDS: d2 dot reads are uniform-broadcast double2 (same values, same
// c-ascending chain order -> bit-exact vs previous rounds).
template <int M>
__global__ __launch_bounds__(256) void code_assign_kernel(
    const double* __restrict__ h, int coff, const float* __restrict__ means,
    float* __restrict__ q, float* __restrict__ idx_out) {
  __shared__ __attribute__((aligned(16))) double msT[M * 32];
  __shared__ float msfT[M * 32];
  __shared__ double msq[M];
  int b = blockIdx.y;
  int tid = threadIdx.x;
  int t = blockIdx.x * 256 + tid;
  for (int i = tid; i < 32 * M; i += 256) {
    int c = i / M, m = i % M;  // means[c][m] -> [m][c]
    float v = means[i];
    msT[m * 32 + c] = (double)v;
    msfT[m * 32 + c] = v;
  }
  __syncthreads();
  if (tid < M) {
    double s = 0.0;
#pragma unroll
    for (int c = 0; c < 32; ++c)
      s = fma(msT[tid * 32 + c], msT[tid * 32 + c], s);
    msq[tid] = s;
  }
  __syncthreads();
  double xv[32];
  double sx = 0.0;
#pragma unroll
  for (int c = 0; c < 32; ++c) {
    xv[c] = h[(b * 64 + coff + c) * TB + t];
    sx = fma(xv[c], xv[c], sx);
  }
  double dmin = 1e300;
  int imin = 0;
  float ssum = 0.f;
  float qv[32];
#pragma unroll
  for (int c = 0; c < 32; ++c) qv[c] = 0.f;
  for (int m = 0; m < M; ++m) {
    const double* mrow = &msT[m * 32];
    double dot = 0.0;
#pragma unroll
    for (int c = 0; c < 32; c += 2) {
      double2 mv = *(const double2*)&mrow[c];
      dot = fma(xv[c], mv.x, dot);
      dot = fma(xv[c + 1], mv.y, dot);
    }
    double d = sx - 2.0 * dot + msq[m];
    float p;
    if (d < dmin) {
      float f = expf((float)(d - dmin));
      ssum *= f;
#pragma unroll
      for (int c = 0; c < 32; ++c) qv[c] *= f;
      dmin = d;
      imin = m;
      p = 1.f;
    } else {
      p = expf((float)(dmin - d));
    }
    ssum += p;
    const float* mfrow = &msfT[m * 32];
#pragma unroll
    for (int c = 0; c < 32; ++c) qv[c] = fmaf(p, mfrow[c], qv[c]);
  }
  float inv = 1.f / ssum;
#pragma unroll
  for (int c = 0; c < 32; ++c) q[(b * 32 + c) * TB + t] = qv[c] * inv;
  idx_out[b * TB + t] = (float)imin;
}

// Split-K FC partial: Z [Mrows][16384], w [512][16384].
__global__ __launch_bounds__(256) void fc_partial_gemm(
    const float* __restrict__ Z, const float* __restrict__ w,
    float* __restrict__ PB, int Mrows) {
  constexpr int BK = 32;
  constexpr int KC = 2048;
  __shared__ float As[BK][68];
  __shared__ float Bs[BK][68];
  int m0 = blockIdx.y * 64;
  int n0 = blockIdx.x * 64;
  int kbase = blockIdx.z * KC;
  int tid = threadIdx.x;
  int row = tid >> 2;
  int kq = (tid & 3) * 4;
  const float* zrow = Z + (size_t)(m0 + row) * 16384 + kbase;
  const float* wrow = w + (size_t)(n0 + row) * 16384 + kbase;
  int mg = tid >> 4;
  int ng = tid & 15;
  float acc[4][4] = {};
  for (int k0 = 0; k0 < KC; k0 += BK) {
    float4 a0 = *(const float4*)&zrow[k0 + kq];
    float4 a1 = *(const float4*)&zrow[k0 + kq + 16];
    float4 b0 = *(const float4*)&wrow[k0 + kq];
    float4 b1 = *(const float4*)&wrow[k0 + kq + 16];
    __syncthreads();
    As[kq + 0][row] = a0.x; As[kq + 1][row] = a0.y;
    As[kq + 2][row] = a0.z; As[kq + 3][row] = a0.w;
    As[kq + 16][row] = a1.x; As[kq + 17][row] = a1.y;
    As[kq + 18][row] = a1.z; As[kq + 19][row] = a1.w;
    Bs[kq + 0][row] = b0.x; Bs[kq + 1][row] = b0.y;
    Bs[kq + 2][row] = b0.z; Bs[kq + 3][row] = b0.w;
    Bs[kq + 16][row] = b1.x; Bs[kq + 17][row] = b1.y;
    Bs[kq + 18][row] = b1.z; Bs[kq + 19][row] = b1.w;
    __syncthreads();
#pragma unroll
    for (int kk = 0; kk < BK; ++kk) {
      float4 av = *(const float4*)&As[kk][mg * 4];
      float4 bv = *(const float4*)&Bs[kk][ng * 4];
      acc[0][0] = fmaf(av.x, bv.x, acc[0][0]);
      acc[0][1] = fmaf(av.x, bv.y, acc[0][1]);
      acc[0][2] = fmaf(av.x, bv.z, acc[0][2]);
      acc[0][3] = fmaf(av.x, bv.w, acc[0][3]);
      acc[1][0] = fmaf(av.y, bv.x, acc[1][0]);
      acc[1][1] = fmaf(av.y, bv.y, acc[1][1]);
      acc[1][2] = fmaf(av.y, bv.z, acc[1][2]);
      acc[1][3] = fmaf(av.y, bv.w, acc[1][3]);
      acc[2][0] = fmaf(av.z, bv.x, acc[2][0]);
      acc[2][1] = fmaf(av.z, bv.y, acc[2][1]);
      acc[2][2] = fmaf(av.z, bv.z, acc[2][2]);
      acc[2][3] = fmaf(av.z, bv.w, acc[2][3]);
      acc[3][0] = fmaf(av.w, bv.x, acc[3][0]);
      acc[3][1] = fmaf(av.w, bv.y, acc[3][1]);
      acc[3][2] = fmaf(av.w, bv.z, acc[3][2]);
      acc[3][3] = fmaf(av.w, bv.w, acc[3][3]);
    }
  }
  float* pbase = PB + (size_t)blockIdx.z * Mrows * 512;
#pragma unroll
  for (int mi = 0; mi < 4; ++mi) {
    float4 v = {acc[mi][0], acc[mi][1], acc[mi][2], acc[mi][3]};
    *(float4*)&pbase[(size_t)(m0 + mg * 4 + mi) * 512 + n0 + ng * 4] = v;
  }
}

// Reduce KS partials + bias + tanh -> out rows (stacked streams)
__global__ __launch_bounds__(256) void fc_reduce_tanh(
    const float* __restrict__ PB, const float* __restrict__ bias,
    float* __restrict__ out, int Mrows, int rps, int c0) {
  constexpr int KS = 8;
  int idx = blockIdx.x * 256 + threadIdx.x;
  int m = idx >> 9, n = idx & 511;
  if (m >= Mrows) return;
  float s = bias[n];
#pragma unroll
  for (int ks = 0; ks < KS; ++ks)
    s += PB[((size_t)ks * Mrows + m) * 512 + n];
  int st = m / rps, rr = m - st * rps;
  out[((size_t)st * 1024 + c0 + rr) * 512 + n] = tanhf(s);
}

extern "C" void kernel_launch(void* const* d_in, const int* in_sizes, int n_in,
                              void* d_out, int out_size, void* d_ws,
                              size_t ws_size, hipStream_t stream) {
  const float* x = (const float*)d_in[0];
  const float* enc0_w1 = (const float*)d_in[1];
  const float* enc0_b1 = (const float*)d_in[2];
  const float* enc0_w2 = (const float*)d_in[3];
  const float* enc0_b2 = (const float*)d_in[4];
  const float* enc0_ws = (const float*)d_in[5];
  const float* enc0_bs = (const float*)d_in[6];
  const float* enc_w = (const float*)d_in[7];
  const float* enc_b = (const float*)d_in[8];
  const float* dec_w = (const float*)d_in[9];
  const float* dec_b = (const float*)d_in[10];
  const float* fc1_w = (const float*)d_in[11];
  const float* fc1_b = (const float*)d_in[12];
  const float* means_s = (const float*)d_in[13];
  const float* means_n = (const float*)d_in[14];

  const size_t WB = 2285568;  // transposed-weight bytes
  int BC = 32;
  for (int c = 512; c >= 32; c >>= 1)
    if (WB + (size_t)c * 524288 <= ws_size) { BC = c; break; }

  double* wT0d = (double*)d_ws;
  double* wTed = wT0d + 36864;
  float* wTdf = (float*)(wTed + 221184);
  double* E0d = (double*)(wTdf + 55296);
  double* E1d = E0d + (size_t)BC * 32768;
  // f32 aliases. E1d region: qs,qn,D0s,D0n. E0d region: Dz(2), T1s, T1n.
  float* qs = (float*)E1d;
  float* qn = qs + (size_t)BC * 16384;
  float* D0s = qn + (size_t)BC * 16384;
  float* D0n = D0s + (size_t)BC * 16384;
  float* Dz = (float*)E0d;
  float* T1s = Dz + (size_t)2 * BC * 16384;
  float* T1n = T1s + (size_t)BC * 16384;
  float* PB = T1s;  // aliases T1s; used only after decoders complete
  float* out = (float*)d_out;

  transpose_w2_f64_kernel<<<dim3(144), 256, 0, stream>>>(enc0_w2, wT0d, 64, 1);
  transpose_w2_f64_kernel<<<dim3(864), 256, 0, stream>>>(enc_w, wTed, 64, 6);
  transpose_w_f32_kernel<<<dim3(216), 256, 0, stream>>>(dec_w, wTdf, 32, 6);

  for (int c0 = 0; c0 < BATCH; c0 += BC) {
    const float* xb = x + (size_t)c0 * TB;

    // encoder (f64)
    enc0_f64_kernel<<<dim3(8, BC), 256, 0, stream>>>(
        xb, enc0_w1, enc0_b1, wT0d, enc0_b2, enc0_ws, enc0_bs, E0d);
    for (int i = 0; i < 3; ++i) {
      conv64_f64_kernel<false><<<dim3(8, BC), 256, 0, stream>>>(
          E0d, wTed + (2 * i) * 36864, enc_b + (2 * i) * 64, nullptr, E1d);
      conv64_f64_kernel<true><<<dim3(8, BC), 256, 0, stream>>>(
          E1d, wTed + (2 * i + 1) * 36864, enc_b + (2 * i + 1) * 64, E0d, E0d);
    }

    // vector-quantize (writes idx outputs directly)
    code_assign_kernel<64><<<dim3(2, BC), 256, 0, stream>>>(
        E0d, 0, means_s, qs, out + 2 * 524288 + (size_t)c0 * TB);
    code_assign_kernel<32><<<dim3(2, BC), 256, 0, stream>>>(
        E0d, 32, means_n, qn, out + 3 * 524288 + (size_t)c0 * TB);

    // decoders (s and n merged via blockIdx.z)
    float* destS = Dz;
    float* destN = Dz + (size_t)BC * 16384;
    conv32z_kernel<false><<<dim3(4, BC, 2), 256, 0, stream>>>(
        qs, qn, wTdf + 0 * 9216, dec_b + 0 * 32, nullptr, nullptr, D0s, D0n);
    conv32z_kernel<true><<<dim3(4, BC, 2), 256, 0, stream>>>(
        D0s, D0n, wTdf + 1 * 9216, dec_b + 1 * 32, qs, qn, T1s, T1n);
    conv32z_kernel<false><<<dim3(4, BC, 2), 256, 0, stream>>>(
        T1s, T1n, wTdf + 2 * 9216, dec_b + 2 * 32, nullptr, nullptr, D0s, D0n);
    conv32z_kernel<true><<<dim3(4, BC, 2), 256, 0, stream>>>(
        D0s, D0n, wTdf + 3 * 9216, dec_b + 3 * 32, T1s, T1n, qs, qn);
    conv32z_kernel<false><<<dim3(4, BC, 2), 256, 0, stream>>>(
        qs, qn, wTdf + 4 * 9216, dec_b + 4 * 32, nullptr, nullptr, D0s, D0n);
    conv32z_kernel<true><<<dim3(4, BC, 2), 256, 0, stream>>>(
        D0s, D0n, wTdf + 5 * 9216, dec_b + 5 * 32, qs, qn, destS, destN);

    // FC: split-K partials + reduce (PB aliases T1s, dead after decoders)
    fc_partial_gemm<<<dim3(8, (2 * BC) / 64, 8), 256, 0, stream>>>(
        Dz, fc1_w, PB, 2 * BC);
    fc_reduce_tanh<<<dim3((2 * BC * 512) / 256), 256, 0, stream>>>(
        PB, fc1_b, out, 2 * BC, BC, c0);
  }
}

// Round 20
// 7886.136 us; speedup vs baseline: 1.3193x; 1.3193x over previous
//
#include <hip/hip_runtime.h>
#include <math.h>

// ---------------------------------------------------------------------------
// AE_control: B=1024, T=512, D=64, K=9, NUM_M=64, NUM_N=32, SCALE=1
// Encoder + argmin in f64 (np reference is f64). Per-chain accumulation:
// bias + cin-ascending, k-ascending (proven across R5/8-17).
// R20: R17 base (unroll 1, VGPR 72 — the banked 7.97ms config) + bit-exact
// code_assign means-transpose [m][c] (broadcast double2 reads) kept from R19.
// Decoder merged (R15), FC split-K. BC=256.
// ---------------------------------------------------------------------------

#define TB 512
#define BATCH 1024

// (nmat, C, C, 9) f32 -> (nmat, C, 9, C) f64: wT2[cin][k][cout]
__global__ __launch_bounds__(256) void transpose_w2_f64_kernel(
    const float* __restrict__ w, double* __restrict__ wT, int C, int nmat) {
  int total = nmat * C * C * 9;
  for (int i = blockIdx.x * blockDim.x + threadIdx.x; i < total;
       i += gridDim.x * blockDim.x) {
    int mat = i / (C * C * 9);
    int r = i % (C * C * 9);
    int cout = r / (C * 9);
    int rem = r % (C * 9);
    int cin = rem / 9;
    int k = rem % 9;
    wT[((mat * C + cin) * 9 + k) * C + cout] = (double)w[i];
  }
}

// (nmat, C, C, 9) f32 -> (nmat, 9, C, C) f32  [k][cin][cout]
__global__ __launch_bounds__(256) void transpose_w_f32_kernel(
    const float* __restrict__ w, float* __restrict__ wT, int C, int nmat) {
  int total = nmat * C * C * 9;
  for (int i = blockIdx.x * blockDim.x + threadIdx.x; i < total;
       i += gridDim.x * blockDim.x) {
    int mat = i / (C * C * 9);
    int r = i % (C * C * 9);
    int cout = r / (C * 9);
    int rem = r % (C * 9);
    int cin = rem / 9;
    int k = rem % 9;
    wT[mat * C * C * 9 + (k * C + cin) * C + cout] = w[i];
  }
}

// Streaming FMA over a 24-double window feeding 16 chains:
// acc[j-k] += w[k]*x[j], j ascending => per-chain k ascending.
template <typename F>
__device__ __forceinline__ void conv64_fma_stream(const double* __restrict__ xr,
                                                  const double (&w)[9],
                                                  F&& upd) {
#pragma unroll
  for (int j2 = 0; j2 < 24; j2 += 2) {
    double2 v = *(const double2*)&xr[j2];
#pragma unroll
    for (int k = 0; k < 9; ++k) {
      int ta = j2 - k;
      if (ta >= 0 && ta < 16) upd(ta, w[k], v.x);
    }
#pragma unroll
    for (int k = 0; k < 9; ++k) {
      int tb = j2 + 1 - k;
      if (tb >= 0 && tb < 16) upd(tb, w[k], v.y);
    }
  }
}

__device__ __forceinline__ void load9(const double* __restrict__ p,
                                      double (&w)[9]) {
#pragma unroll
  for (int k = 0; k < 9; ++k) w[k] = p[k * 64];
}

// 32-cin range of the conv body: lane = cout, wslab = 16-t slab.
// xs: LDS [64][72]. wT2: global [cin][9][64]. 2-buffer weight prefetch.
__device__ __forceinline__ void conv64_body_range(
    const double* __restrict__ xs, const double* __restrict__ wT2,
    double acc[16], int lane, int wslab, int cin0) {
  const double* wp0 = wT2 + lane;
  const double* xb = xs + wslab * 16;
  double wA[9], wB[9];
  load9(wp0 + cin0 * 576, wA);
  auto upd = [&](int t, double w, double x) { acc[t] = fma(w, x, acc[t]); };
#pragma unroll 1
  for (int cin = cin0; cin < cin0 + 32; cin += 2) {
    load9(wp0 + (cin + 1) * 576, wB);
    conv64_fma_stream(xb + cin * 72, wA, upd);
    if (cin + 2 < cin0 + 32) load9(wp0 + (cin + 2) * 576, wA);
    conv64_fma_stream(xb + (cin + 1) * 72, wB, upd);
  }
}

// enc0 fused block (f64): x f32 (BC,512) -> out f64 (BC,64,512). 256 thr.
__global__ __launch_bounds__(256, 1) void enc0_f64_kernel(
    const float* __restrict__ x, const float* __restrict__ w1,
    const float* __restrict__ b1, const double* __restrict__ w2T,
    const float* __restrict__ b2, const float* __restrict__ wsc,
    const float* __restrict__ bsc, double* __restrict__ out) {
  __shared__ double xs0[80];
  __shared__ double w1s[576];
  __shared__ double b1s[64];
  __shared__ double mid[64 * 72];
  int b = blockIdx.y;
  int t0 = blockIdx.x * 64;
  int tid = threadIdx.x;
  if (tid < 80) {
    int t = t0 - 8 + tid;
    xs0[tid] = (t >= 0 && t < TB) ? (double)x[b * TB + t] : 0.0;
  }
  for (int i = tid; i < 576; i += 256) w1s[i] = (double)w1[i];
  if (tid < 64) b1s[tid] = (double)b1[tid];
  __syncthreads();
  for (int e = tid; e < 64 * 72; e += 256) {
    int cout = e / 72, tt = e % 72;
    int t = t0 - 4 + tt;
    double acc = b1s[cout];
#pragma unroll
    for (int k = 0; k < 9; ++k) acc = fma(w1s[cout * 9 + k], xs0[tt + k], acc);
    mid[e] = (t >= 0 && t < TB) ? fmax(acc, 0.0) : 0.0;
  }
  __syncthreads();
  int wave = tid >> 6;
  int lane = tid & 63;
  double acc[16];
  double bz = (double)b2[lane];
#pragma unroll
  for (int t = 0; t < 16; ++t) acc[t] = bz;
  conv64_body_range(mid, w2T, acc, lane, wave, 0);
  conv64_body_range(mid, w2T, acc, lane, wave, 32);
  __syncthreads();  // mid reads done; reuse as transpose buffer [64][65]
  double* T = mid;
#pragma unroll
  for (int t = 0; t < 16; ++t) T[lane * 65 + wave * 16 + t] = acc[t];
  __syncthreads();
  for (int i = tid; i < 4096; i += 256) {
    int cout = i >> 6, tt = i & 63;
    double v = T[cout * 65 + tt] +
               fma((double)wsc[cout], xs0[8 + tt], (double)bsc[cout]);
    out[(b * 64 + cout) * TB + t0 + tt] = fmax(v, 0.0);
  }
}

// f64 conv 64->64, K=9, SAME. 256 thr, 4 waves x 16-t slabs (R17 shape).
template <bool SKIP>
__global__ __launch_bounds__(256, 1) void conv64_f64_kernel(
    const double* __restrict__ in, const double* __restrict__ wT2,
    const float* __restrict__ bias, const double* __restrict__ skip,
    double* __restrict__ out) {
  __shared__ double xs[64 * 72];
  int b = blockIdx.y;
  int t0 = blockIdx.x * 64;
  int tid = threadIdx.x;
  for (int i = tid; i < 64 * 72; i += 256) {
    int cin = i / 72, tt = i % 72;
    int t = t0 - 4 + tt;
    xs[i] = (t >= 0 && t < TB) ? in[(b * 64 + cin) * TB + t] : 0.0;
  }
  __syncthreads();
  int wave = tid >> 6;
  int lane = tid & 63;
  double acc[16];
  double bz = (double)bias[lane];
#pragma unroll
  for (int t = 0; t < 16; ++t) acc[t] = bz;
  conv64_body_range(xs, wT2, acc, lane, wave, 0);
  conv64_body_range(xs, wT2, acc, lane, wave, 32);
  __syncthreads();  // xs reads done; reuse as transpose buffer [64][65]
  double* T = xs;
#pragma unroll
  for (int t = 0; t < 16; ++t) T[lane * 65 + wave * 16 + t] = acc[t];
  __syncthreads();
  for (int i = tid; i < 4096; i += 256) {
    int cout = i >> 6, tt = i & 63;
    double v = T[cout * 65 + tt];
    if constexpr (SKIP) v += skip[(b * 64 + cout) * TB + t0 + tt];
    out[(b * 64 + cout) * TB + t0 + tt] = fmax(v, 0.0);
  }
}

// f32 conv 32->32 (decoder), K=9, SAME; blockIdx.z selects stream s/n.
template <bool SKIP>
__global__ __launch_bounds__(256) void conv32z_kernel(
    const float* __restrict__ in0, const float* __restrict__ in1,
    const float* __restrict__ wT, const float* __restrict__ bias,
    const float* __restrict__ sk0, const float* __restrict__ sk1,
    float* __restrict__ o0, float* __restrict__ o1) {
  constexpr int XW = 136;
  __shared__ float xs[32 * XW];
  const float* in = blockIdx.z ? in1 : in0;
  const float* skip = blockIdx.z ? sk1 : sk0;
  float* out = blockIdx.z ? o1 : o0;
  int b = blockIdx.y;
  int t0 = blockIdx.x * 128;
  int tid = threadIdx.x;
  for (int i = tid; i < 32 * XW; i += 256) {
    int cin = i / XW, tt = i % XW;
    int t = t0 - 4 + tt;
    xs[i] = (t >= 0 && t < TB) ? in[(b * 32 + cin) * TB + t] : 0.f;
  }
  __syncthreads();
  int wave = __builtin_amdgcn_readfirstlane(tid >> 6);
  int lane = tid & 63;
  int cbase = (wave & 1) * 16;
  int ttl = (wave >> 1) * 64 + lane;
  float acc[16];
#pragma unroll
  for (int j = 0; j < 16; ++j) acc[j] = bias[cbase + j];
  for (int cin = 0; cin < 32; ++cin) {
#pragma unroll
    for (int k = 0; k < 9; ++k) {
      float xv = xs[cin * XW + ttl + k];
      const float* wp = wT + (k * 32 + cin) * 32 + cbase;
#pragma unroll
      for (int j = 0; j < 16; ++j) acc[j] = fmaf(xv, wp[j], acc[j]);
    }
  }
  int t = t0 + ttl;
#pragma unroll
  for (int j = 0; j < 16; ++j) {
    float v = acc[j];
    if constexpr (SKIP) v += skip[(b * 32 + cbase + j) * TB + t];
    out[(b * 32 + cbase + j) * TB + t] = fmaxf(v, 0.f);
  }
}

// code_assign (f64 distances/argmin, f32 q). Means transposed to [m][c] in
// LDS: broadcast double2 reads; same values, same c-ascending chain order.
template <int M>
__global__ __launch_bounds__(256) void code_assign_kernel(
    const double* __restrict__ h, int coff, const float* __restrict__ means,
    float* __restrict__ q, float* __restrict__ idx_out) {
  __shared__ __attribute__((aligned(16))) double msT[M * 32];
  __shared__ float msfT[M * 32];
  __shared__ double msq[M];
  int b = blockIdx.y;
  int tid = threadIdx.x;
  int t = blockIdx.x * 256 + tid;
  for (int i = tid; i < 32 * M; i += 256) {
    int c = i / M, m = i % M;  // means[c][m] -> [m][c]
    float v = means[i];
    msT[m * 32 + c] = (double)v;
    msfT[m * 32 + c] = v;
  }
  __syncthreads();
  if (tid < M) {
    double s = 0.0;
#pragma unroll
    for (int c = 0; c < 32; ++c)
      s = fma(msT[tid * 32 + c], msT[tid * 32 + c], s);
    msq[tid] = s;
  }
  __syncthreads();
  double xv[32];
  double sx = 0.0;
#pragma unroll
  for (int c = 0; c < 32; ++c) {
    xv[c] = h[(b * 64 + coff + c) * TB + t];
    sx = fma(xv[c], xv[c], sx);
  }
  double dmin = 1e300;
  int imin = 0;
  float ssum = 0.f;
  float qv[32];
#pragma unroll
  for (int c = 0; c < 32; ++c) qv[c] = 0.f;
  for (int m = 0; m < M; ++m) {
    const double* mrow = &msT[m * 32];
    double dot = 0.0;
#pragma unroll
    for (int c = 0; c < 32; c += 2) {
      double2 mv = *(const double2*)&mrow[c];
      dot = fma(xv[c], mv.x, dot);
      dot = fma(xv[c + 1], mv.y, dot);
    }
    double d = sx - 2.0 * dot + msq[m];
    float p;
    if (d < dmin) {
      float f = expf((float)(d - dmin));
      ssum *= f;
#pragma unroll
      for (int c = 0; c < 32; ++c) qv[c] *= f;
      dmin = d;
      imin = m;
      p = 1.f;
    } else {
      p = expf((float)(dmin - d));
    }
    ssum += p;
    const float* mfrow = &msfT[m * 32];
#pragma unroll
    for (int c = 0; c < 32; ++c) qv[c] = fmaf(p, mfrow[c], qv[c]);
  }
  float inv = 1.f / ssum;
#pragma unroll
  for (int c = 0; c < 32; ++c) q[(b * 32 + c) * TB + t] = qv[c] * inv;
  idx_out[b * TB + t] = (float)imin;
}

// Split-K FC partial: Z [Mrows][16384], w [512][16384].
__global__ __launch_bounds__(256) void fc_partial_gemm(
    const float* __restrict__ Z, const float* __restrict__ w,
    float* __restrict__ PB, int Mrows) {
  constexpr int BK = 32;
  constexpr int KC = 2048;
  __shared__ float As[BK][68];
  __shared__ float Bs[BK][68];
  int m0 = blockIdx.y * 64;
  int n0 = blockIdx.x * 64;
  int kbase = blockIdx.z * KC;
  int tid = threadIdx.x;
  int row = tid >> 2;
  int kq = (tid & 3) * 4;
  const float* zrow = Z + (size_t)(m0 + row) * 16384 + kbase;
  const float* wrow = w + (size_t)(n0 + row) * 16384 + kbase;
  int mg = tid >> 4;
  int ng = tid & 15;
  float acc[4][4] = {};
  for (int k0 = 0; k0 < KC; k0 += BK) {
    float4 a0 = *(const float4*)&zrow[k0 + kq];
    float4 a1 = *(const float4*)&zrow[k0 + kq + 16];
    float4 b0 = *(const float4*)&wrow[k0 + kq];
    float4 b1 = *(const float4*)&wrow[k0 + kq + 16];
    __syncthreads();
    As[kq + 0][row] = a0.x; As[kq + 1][row] = a0.y;
    As[kq + 2][row] = a0.z; As[kq + 3][row] = a0.w;
    As[kq + 16][row] = a1.x; As[kq + 17][row] = a1.y;
    As[kq + 18][row] = a1.z; As[kq + 19][row] = a1.w;
    Bs[kq + 0][row] = b0.x; Bs[kq + 1][row] = b0.y;
    Bs[kq + 2][row] = b0.z; Bs[kq + 3][row] = b0.w;
    Bs[kq + 16][row] = b1.x; Bs[kq + 17][row] = b1.y;
    Bs[kq + 18][row] = b1.z; Bs[kq + 19][row] = b1.w;
    __syncthreads();
#pragma unroll
    for (int kk = 0; kk < BK; ++kk) {
      float4 av = *(const float4*)&As[kk][mg * 4];
      float4 bv = *(const float4*)&Bs[kk][ng * 4];
      acc[0][0] = fmaf(av.x, bv.x, acc[0][0]);
      acc[0][1] = fmaf(av.x, bv.y, acc[0][1]);
      acc[0][2] = fmaf(av.x, bv.z, acc[0][2]);
      acc[0][3] = fmaf(av.x, bv.w, acc[0][3]);
      acc[1][0] = fmaf(av.y, bv.x, acc[1][0]);
      acc[1][1] = fmaf(av.y, bv.y, acc[1][1]);
      acc[1][2] = fmaf(av.y, bv.z, acc[1][2]);
      acc[1][3] = fmaf(av.y, bv.w, acc[1][3]);
      acc[2][0] = fmaf(av.z, bv.x, acc[2][0]);
      acc[2][1] = fmaf(av.z, bv.y, acc[2][1]);
      acc[2][2] = fmaf(av.z, bv.z, acc[2][2]);
      acc[2][3] = fmaf(av.z, bv.w, acc[2][3]);
      acc[3][0] = fmaf(av.w, bv.x, acc[3][0]);
      acc[3][1] = fmaf(av.w, bv.y, acc[3][1]);
      acc[3][2] = fmaf(av.w, bv.z, acc[3][2]);
      acc[3][3] = fmaf(av.w, bv.w, acc[3][3]);
    }
  }
  float* pbase = PB + (size_t)blockIdx.z * Mrows * 512;
#pragma unroll
  for (int mi = 0; mi < 4; ++mi) {
    float4 v = {acc[mi][0], acc[mi][1], acc[mi][2], acc[mi][3]};
    *(float4*)&pbase[(size_t)(m0 + mg * 4 + mi) * 512 + n0 + ng * 4] = v;
  }
}

// Reduce KS partials + bias + tanh -> out rows (stacked streams)
__global__ __launch_bounds__(256) void fc_reduce_tanh(
    const float* __restrict__ PB, const float* __restrict__ bias,
    float* __restrict__ out, int Mrows, int rps, int c0) {
  constexpr int KS = 8;
  int idx = blockIdx.x * 256 + threadIdx.x;
  int m = idx >> 9, n = idx & 511;
  if (m >= Mrows) return;
  float s = bias[n];
#pragma unroll
  for (int ks = 0; ks < KS; ++ks)
    s += PB[((size_t)ks * Mrows + m) * 512 + n];
  int st = m / rps, rr = m - st * rps;
  out[((size_t)st * 1024 + c0 + rr) * 512 + n] = tanhf(s);
}

extern "C" void kernel_launch(void* const* d_in, const int* in_sizes, int n_in,
                              void* d_out, int out_size, void* d_ws,
                              size_t ws_size, hipStream_t stream) {
  const float* x = (const float*)d_in[0];
  const float* enc0_w1 = (const float*)d_in[1];
  const float* enc0_b1 = (const float*)d_in[2];
  const float* enc0_w2 = (const float*)d_in[3];
  const float* enc0_b2 = (const float*)d_in[4];
  const float* enc0_ws = (const float*)d_in[5];
  const float* enc0_bs = (const float*)d_in[6];
  const float* enc_w = (const float*)d_in[7];
  const float* enc_b = (const float*)d_in[8];
  const float* dec_w = (const float*)d_in[9];
  const float* dec_b = (const float*)d_in[10];
  const float* fc1_w = (const float*)d_in[11];
  const float* fc1_b = (const float*)d_in[12];
  const float* means_s = (const float*)d_in[13];
  const float* means_n = (const float*)d_in[14];

  const size_t WB = 2285568;  // transposed-weight bytes
  int BC = 32;
  for (int c = 512; c >= 32; c >>= 1)
    if (WB + (size_t)c * 524288 <= ws_size) { BC = c; break; }

  double* wT0d = (double*)d_ws;
  double* wTed = wT0d + 36864;
  float* wTdf = (float*)(wTed + 221184);
  double* E0d = (double*)(wTdf + 55296);
  double* E1d = E0d + (size_t)BC * 32768;
  // f32 aliases. E1d region: qs,qn,D0s,D0n. E0d region: Dz(2), T1s, T1n.
  float* qs = (float*)E1d;
  float* qn = qs + (size_t)BC * 16384;
  float* D0s = qn + (size_t)BC * 16384;
  float* D0n = D0s + (size_t)BC * 16384;
  float* Dz = (float*)E0d;
  float* T1s = Dz + (size_t)2 * BC * 16384;
  float* T1n = T1s + (size_t)BC * 16384;
  float* PB = T1s;  // aliases T1s; used only after decoders complete
  float* out = (float*)d_out;

  transpose_w2_f64_kernel<<<dim3(144), 256, 0, stream>>>(enc0_w2, wT0d, 64, 1);
  transpose_w2_f64_kernel<<<dim3(864), 256, 0, stream>>>(enc_w, wTed, 64, 6);
  transpose_w_f32_kernel<<<dim3(216), 256, 0, stream>>>(dec_w, wTdf, 32, 6);

  for (int c0 = 0; c0 < BATCH; c0 += BC) {
    const float* xb = x + (size_t)c0 * TB;

    // encoder (f64)
    enc0_f64_kernel<<<dim3(8, BC), 256, 0, stream>>>(
        xb, enc0_w1, enc0_b1, wT0d, enc0_b2, enc0_ws, enc0_bs, E0d);
    for (int i = 0; i < 3; ++i) {
      conv64_f64_kernel<false><<<dim3(8, BC), 256, 0, stream>>>(
          E0d, wTed + (2 * i) * 36864, enc_b + (2 * i) * 64, nullptr, E1d);
      conv64_f64_kernel<true><<<dim3(8, BC), 256, 0, stream>>>(
          E1d, wTed + (2 * i + 1) * 36864, enc_b + (2 * i + 1) * 64, E0d, E0d);
    }

    // vector-quantize (writes idx outputs directly)
    code_assign_kernel<64><<<dim3(2, BC), 256, 0, stream>>>(
        E0d, 0, means_s, qs, out + 2 * 524288 + (size_t)c0 * TB);
    code_assign_kernel<32><<<dim3(2, BC), 256, 0, stream>>>(
        E0d, 32, means_n, qn, out + 3 * 524288 + (size_t)c0 * TB);

    // decoders (s and n merged via blockIdx.z)
    float* destS = Dz;
    float* destN = Dz + (size_t)BC * 16384;
    conv32z_kernel<false><<<dim3(4, BC, 2), 256, 0, stream>>>(
        qs, qn, wTdf + 0 * 9216, dec_b + 0 * 32, nullptr, nullptr, D0s, D0n);
    conv32z_kernel<true><<<dim3(4, BC, 2), 256, 0, stream>>>(
        D0s, D0n, wTdf + 1 * 9216, dec_b + 1 * 32, qs, qn, T1s, T1n);
    conv32z_kernel<false><<<dim3(4, BC, 2), 256, 0, stream>>>(
        T1s, T1n, wTdf + 2 * 9216, dec_b + 2 * 32, nullptr, nullptr, D0s, D0n);
    conv32z_kernel<true><<<dim3(4, BC, 2), 256, 0, stream>>>(
        D0s, D0n, wTdf + 3 * 9216, dec_b + 3 * 32, T1s, T1n, qs, qn);
    conv32z_kernel<false><<<dim3(4, BC, 2), 256, 0, stream>>>(
        qs, qn, wTdf + 4 * 9216, dec_b + 4 * 32, nullptr, nullptr, D0s, D0n);
    conv32z_kernel<true><<<dim3(4, BC, 2), 256, 0, stream>>>(
        D0s, D0n, wTdf + 5 * 9216, dec_b + 5 * 32, qs, qn, destS, destN);

    // FC: split-K partials + reduce (PB aliases T1s, dead after decoders)
    fc_partial_gemm<<<dim3(8, (2 * BC) / 64, 8), 256, 0, stream>>>(
        Dz, fc1_w, PB, 2 * BC);
    fc_reduce_tanh<<<dim3((2 * BC * 512) / 256), 256, 0, stream>>>(
        PB, fc1_b, out, 2 * BC, BC, c0);
  }
}